// Round 19
// baseline (29.828 us; speedup 1.0000x reference)
//
#include <hip/hip_runtime.h>
#include <hip/hip_bf16.h>
#include <math.h>

// ============================================================================
// MemN2N forward — final structure (R16, best measured: 29.78 us)
//   node1 k_embed: query+story embedding gathers (960 blocks x 128)
//   node2 k_hops : 3 memory hops, 160 blocks x 512 (8 waves), 5 bars/hop
//   node3 k_out  : [160x32000] classifier GEMM via bf16 MFMA, zero-overfetch
// Budget (amplification-measured): OH~15.5 (3-node graph replay, structurally
// minimal — cross-block sync 3x catastrophic: R6/R14/R18), E~3.6 (gather
// latency floor), H~6.3 (best of 8 variants), O~4.2 (write floor).
// ============================================================================

#define EMBED 128
#define VOCAB 32000
#define MEMN  50
#define BATCH 16
#define NQ    10
#define SQ    20
#define SS    40
#define BN    (BATCH*NQ)   // 160
#define NHOPS 3
#define NV    64           // vocab rows per k_out block
#define NST   (BATCH*MEMN) // 800

typedef short v8s __attribute__((ext_vector_type(8)));
typedef float v4f __attribute__((ext_vector_type(4)));

#define MFMA16 __builtin_amdgcn_mfma_f32_16x16x32_bf16

__device__ __forceinline__ float posw(int j, int J, int k) {
    float jf = (float)(j + 1) / (float)J;
    return 1.0f - jf - ((float)(k + 1) / (float)EMBED) * (1.0f - 2.0f * jf);
}

__device__ __forceinline__ short f2bf(float f) {
    __hip_bfloat16 h = __float2bfloat16(f);
    return *(short*)&h;
}

// ---- Kernel 1: query | story embedding ----
__global__ void k_embed(const int* __restrict__ cq, const int* __restrict__ story,
                        const float* __restrict__ Bw, const float* __restrict__ Aw,
                        const float* __restrict__ Cw, const float* __restrict__ TA,
                        const float* __restrict__ TC,
                        float* __restrict__ state, float* __restrict__ memb,
                        float* __restrict__ outb) {
    int blk = blockIdx.x;
    int t = threadIdx.x;   // 128
    if (blk < BN) {
        float acc = 0.f;
        #pragma unroll
        for (int s = 0; s < SQ; ++s) {
            int tok = cq[blk * SQ + s];
            acc += Bw[tok * EMBED + t] * posw(s, SQ, t);
        }
        state[blk * EMBED + t] = acc;
    } else {
        int br = blk - BN;
        int r = br % MEMN;
        float ma = TA[r * EMBED + t];
        float mc = TC[r * EMBED + t];
        const int* toks = story + br * SS;
        #pragma unroll 4
        for (int s = 0; s < SS; ++s) {
            int tok = toks[s];
            float w = posw(s, SS, t);
            ma += Aw[tok * EMBED + t] * w;
            mc += Cw[tok * EMBED + t] * w;
        }
        memb[br * EMBED + t] = ma;
        outb[br * EMBED + t] = mc;
    }
}

// ---- Kernel 2 (v7): 8-wave hops. Logits split-K-8, resp/H 4-way splits. ----
__global__ __launch_bounds__(512) void k_hops(const float* __restrict__ memb,
                                              const float* __restrict__ outb,
                                              const float* __restrict__ Hw,
                                              const float* __restrict__ Hb,
                                              const float* __restrict__ state,
                                              __hip_bfloat16* __restrict__ stateb) {
    __shared__ float lmem[MEMN][EMBED + 1];
    __shared__ float lout[MEMN][EMBED + 1];
    __shared__ float lstate[EMBED];
    __shared__ float lpart[8][52];
    __shared__ float lprobs[52];
    __shared__ float lrespp[4][EMBED];
    __shared__ float lHp[4][EMBED];

    int bn = blockIdx.x;
    int b  = bn / NQ;
    int t  = threadIdx.x;   // 512
    int w  = t >> 6;        // wave 0..7
    int l  = t & 63;
    int d  = t & 127;
    int g  = t >> 7;        // quarter 0..3

    {
        const float4* mb4 = (const float4*)(memb + (size_t)b * MEMN * EMBED);
        const float4* ob4 = (const float4*)(outb + (size_t)b * MEMN * EMBED);
        for (int i = t; i < MEMN * EMBED / 4; i += 512) {
            int r = i >> 5, c = (i & 31) << 2;
            float4 v = mb4[i];
            lmem[r][c] = v.x; lmem[r][c+1] = v.y; lmem[r][c+2] = v.z; lmem[r][c+3] = v.w;
            float4 u = ob4[i];
            lout[r][c] = u.x; lout[r][c+1] = u.y; lout[r][c+2] = u.z; lout[r][c+3] = u.w;
        }
        if (t < EMBED) lstate[t] = state[bn * EMBED + t];
    }
    float hbd = (t < EMBED) ? Hb[t] : 0.f;
    __syncthreads();

    for (int hop = 0; hop < NHOPS; ++hop) {
        // logits split-K-8: wave w covers dims [w*16, w*16+16), lane l = row
        if (l < MEMN) {
            int d0 = w << 4;
            float a0 = 0.f, a1 = 0.f, a2 = 0.f, a3 = 0.f;
            #pragma unroll
            for (int j = 0; j < 16; j += 4) {
                a0 += lmem[l][d0 + j]     * lstate[d0 + j];
                a1 += lmem[l][d0 + j + 1] * lstate[d0 + j + 1];
                a2 += lmem[l][d0 + j + 2] * lstate[d0 + j + 2];
                a3 += lmem[l][d0 + j + 3] * lstate[d0 + j + 3];
            }
            lpart[w][l] = (a0 + a1) + (a2 + a3);
        }
        __syncthreads();
        // softmax in wave 0
        if (t < 64) {
            float lg = -1e30f;
            if (t < MEMN) {
                float s0 = (lpart[0][t] + lpart[1][t]) + (lpart[2][t] + lpart[3][t]);
                float s1 = (lpart[4][t] + lpart[5][t]) + (lpart[6][t] + lpart[7][t]);
                lg = s0 + s1;
            }
            float mx = lg;
            #pragma unroll
            for (int off = 32; off; off >>= 1) mx = fmaxf(mx, __shfl_xor(mx, off, 64));
            float e = (t < MEMN) ? __expf(lg - mx) : 0.f;
            float ss = e;
            #pragma unroll
            for (int off = 32; off; off >>= 1) ss += __shfl_xor(ss, off, 64);
            if (t < MEMN) lprobs[t] = e / ss;
        }
        __syncthreads();
        // response 4-way: quarter g covers rows {g, g+4, ...}
        {
            float r0 = 0.f, r1 = 0.f;
            #pragma unroll
            for (int k = 0; k + 4 < MEMN; k += 8) {
                int ra = g + k, rb = g + k + 4;
                r0 += lprobs[ra] * lout[ra][d];
                r1 += lprobs[rb] * lout[rb][d];
            }
            if (g < 2) { int ra = g + 48; r0 += lprobs[ra] * lout[ra][d]; }
            lrespp[g][d] = r0 + r1;
        }
        __syncthreads();
        // H 4-way: quarter g covers k in [g*32, g*32+32); lrespp reads broadcast
        {
            int ks = g << 5;
            const float4* hw4 = (const float4*)&Hw[(size_t)d * EMBED + ks];
            float a0 = 0.f, a1 = 0.f, a2 = 0.f, a3 = 0.f;
            #pragma unroll
            for (int j = 0; j < 8; ++j) {
                float4 wv = hw4[j];
                int k = ks + (j << 2);
                float v0 = (lrespp[0][k]     + lrespp[1][k])     + (lrespp[2][k]     + lrespp[3][k]);
                float v1 = (lrespp[0][k + 1] + lrespp[1][k + 1]) + (lrespp[2][k + 1] + lrespp[3][k + 1]);
                float v2 = (lrespp[0][k + 2] + lrespp[1][k + 2]) + (lrespp[2][k + 2] + lrespp[3][k + 2]);
                float v3 = (lrespp[0][k + 3] + lrespp[1][k + 3]) + (lrespp[2][k + 3] + lrespp[3][k + 3]);
                a0 += v0 * wv.x; a1 += v1 * wv.y; a2 += v2 * wv.z; a3 += v3 * wv.w;
            }
            lHp[g][d] = (a0 + a1) + (a2 + a3);
        }
        __syncthreads();
        if (t < EMBED) {
            float ns = hbd + lstate[t]
                     + (lHp[0][t] + lHp[1][t]) + (lHp[2][t] + lHp[3][t]);
            lstate[t] = ns;
        }
        __syncthreads();
    }
    if (t < EMBED)
        stateb[bn * EMBED + t] = __float2bfloat16(lstate[t]);
}

// ---- Kernel 3: MFMA GEMM out[160,32000] ----
__global__ __launch_bounds__(256) void k_out(const __hip_bfloat16* __restrict__ stateb,
                                             const float* __restrict__ outw,
                                             float* __restrict__ out) {
    __shared__ __align__(16) __hip_bfloat16 Alds[BN][EMBED + 8];
    __shared__ __align__(16) __hip_bfloat16 Blds[NV][EMBED + 8];
    int t = threadIdx.x;
    int vbase = blockIdx.x * NV;

    #pragma unroll
    for (int i = 0; i < 10; ++i) {
        int e = t + i * 256;
        int row = e >> 4, c8 = (e & 15) << 3;
        *(int4*)&Alds[row][c8] = *(const int4*)&stateb[row * EMBED + c8];
    }
    #pragma unroll
    for (int i = 0; i < 8; ++i) {
        int e = t + i * 256;
        int row = e >> 5, c4 = (e & 31) << 2;
        float4 w = *(const float4*)&outw[(size_t)(vbase + row) * EMBED + c4];
        short4 p;
        p.x = f2bf(w.x); p.y = f2bf(w.y); p.z = f2bf(w.z); p.w = f2bf(w.w);
        *(short4*)&Blds[row][c4] = p;
    }
    __syncthreads();

    int wv = t >> 6;
    int l = t & 63;
    int col16 = l & 15;
    int kg = l >> 4;

    v8s bfrag[4];
    #pragma unroll
    for (int k4 = 0; k4 < 4; ++k4)
        bfrag[k4] = *(v8s*)&Blds[(wv << 4) + col16][k4 * 32 + kg * 8];

    v4f acc[10];
    #pragma unroll
    for (int m = 0; m < 10; ++m) acc[m] = (v4f){0.f, 0.f, 0.f, 0.f};

    #pragma unroll
    for (int k4 = 0; k4 < 4; ++k4) {
        #pragma unroll
        for (int m = 0; m < 10; ++m) {
            v8s af = *(v8s*)&Alds[m * 16 + col16][k4 * 32 + kg * 8];
            acc[m] = MFMA16(af, bfrag[k4], acc[m], 0, 0, 0);
        }
    }

    int colg = vbase + (wv << 4) + col16;
    #pragma unroll
    for (int m = 0; m < 10; ++m) {
        #pragma unroll
        for (int i = 0; i < 4; ++i) {
            out[(size_t)(m * 16 + kg * 4 + i) * VOCAB + colg] = acc[m][i];
        }
    }
}

extern "C" void kernel_launch(void* const* d_in, const int* in_sizes, int n_in,
                              void* d_out, int out_size, void* d_ws, size_t ws_size,
                              hipStream_t stream) {
    const int*   ctx_query = (const int*)  d_in[0];
    const int*   story     = (const int*)  d_in[1];
    const float* A_w       = (const float*)d_in[2];
    const float* C_w       = (const float*)d_in[3];
    const float* B_w       = (const float*)d_in[4];
    const float* H_w       = (const float*)d_in[5];
    const float* H_b       = (const float*)d_in[6];
    const float* out_w     = (const float*)d_in[7];
    const float* TA        = (const float*)d_in[8];
    const float* TC        = (const float*)d_in[9];
    float* out = (float*)d_out;

    float* ws    = (float*)d_ws;
    float* state = ws;                                   // 160*128 f32
    float* memb  = state + BN * EMBED;                   // 800*128 f32
    float* outb  = memb + NST * EMBED;                   // 800*128 f32
    __hip_bfloat16* stateb = (__hip_bfloat16*)(outb + NST * EMBED); // 160*128 bf16

    k_embed<<<BN + NST, 128, 0, stream>>>(
        ctx_query, story, B_w, A_w, C_w, TA, TC, state, memb, outb);
    k_hops<<<BN, 512, 0, stream>>>(memb, outb, H_w, H_b, state, stateb);
    k_out<<<VOCAB / NV, 256, 0, stream>>>(stateb, out_w, out);
}